// Round 3
// baseline (545.996 us; speedup 1.0000x reference)
//
#include <hip/hip_runtime.h>
#include <hip/hip_cooperative_groups.h>

namespace cg = cooperative_groups;

#define Hh 240
#define Ww 304
#define IN_CH 16
#define OUT_CH 32
#define Bb 8
#define N_PER 65536
#define N_EV (Bb * N_PER)      // 524288
#define CIN (IN_CH + 2)        // 18
#define NSEG (Bb * Hh * Ww)    // 583680 = 570 * 1024
#define NBLK 570               // scan blocks of 1024 elems

#define COOP_BLOCKS 1024
#define COOP_THREADS 256
#define COOP_TOTAL (COOP_BLOCKS * COOP_THREADS)  // 262144 = N_EV/2

// fused conv tiling
#define TW 32
#define TH 8
#define HW_ 34                 // TW + 2 halo
#define HH_ 10                 // TH + 2 halo
#define NXT_TILES 10           // ceil(304/32)
#define NYT_TILES 30           // 240/8
#define OPITCH 33              // out repack pitch (f32)

typedef __attribute__((ext_vector_type(8))) short bf16x8;
typedef __attribute__((ext_vector_type(4))) float f32x4;

__device__ __forceinline__ unsigned short f2bf(float x) {
  unsigned u = __float_as_uint(x);
  unsigned r = u + 0x7fffu + ((u >> 16) & 1u);  // RNE
  return (unsigned short)(r >> 16);
}
__device__ __forceinline__ float bf2f(unsigned short b) {
  return __uint_as_float(((unsigned)b) << 16);
}
__device__ __forceinline__ unsigned pk2(float a, float b) {
  return (unsigned)f2bf(a) | ((unsigned)f2bf(b) << 16);
}

// ---- P: one cooperative kernel for the whole prologue ----------------------
// phases: A zero-hist | B hist+rank+pack(regs) | C scan1 + weights | D scan2
//         | E register-sourced payload scatter.   Replaces 6 dispatches.
__global__ __launch_bounds__(256, 4) void prep_kernel(
    const float* __restrict__ events, const float* __restrict__ features,
    const float* __restrict__ weight, const int* __restrict__ offsets,
    int* __restrict__ hist, int* __restrict__ baseLocal,
    int* __restrict__ blockOffset, int* __restrict__ blockSum,
    unsigned short* __restrict__ wprep, uint4* __restrict__ sortedFeat,
    int* __restrict__ sortedMeta) {
  cg::grid_group grid = cg::this_grid();
  __shared__ int lds[256];
  int tid = threadIdx.x;
  int gtid = blockIdx.x * COOP_THREADS + tid;  // 0..262143

  // ---- phase A: zero hist (NSEG = 145920 int4) ----
  for (int i = gtid; i < NSEG / 4; i += COOP_TOTAL)
    ((int4*)hist)[i] = make_int4(0, 0, 0, 0);
  grid.sync();

  // ---- phase B: per-event key/rank + bf16 pack, all kept in registers ----
  int key[2], rank[2];
  uint4 w0[2], w1[2];
#pragma unroll
  for (int s = 0; s < 2; s++) {
    int i = gtid + s * COOP_TOTAL;
    float4 ev = ((const float4*)events)[i];
    int yi = min(max((int)rintf(ev.y * (float)Hh), 0), Hh - 1);
    int xi = min(max((int)rintf(ev.x * (float)Ww), 0), Ww - 1);
    int b = 0;
#pragma unroll
    for (int j = 0; j < Bb; j++) b += (offsets[j] <= i) ? 1 : 0;
    int k = (b * Hh + yi) * Ww + xi;
    rank[s] = atomicAdd(&hist[k], 1);
    key[s] = k | ((ev.w != 0.0f) ? (int)0x80000000 : 0);
    const float4* f = (const float4*)(features + (size_t)i * IN_CH);
    float4 f0 = f[0], f1 = f[1], f2 = f[2], f3 = f[3];
    w0[s].x = pk2(f0.x, f0.y); w0[s].y = pk2(f0.z, f0.w);
    w0[s].z = pk2(f1.x, f1.y); w0[s].w = pk2(f1.z, f1.w);
    w1[s].x = pk2(f2.x, f2.y); w1[s].y = pk2(f2.z, f2.w);
    w1[s].z = pk2(f3.x, f3.y); w1[s].w = pk2(f3.z, f3.w);
  }
  grid.sync();

  // ---- phase C: scan1 on blocks 0..569; weight pack on block 570 ----
  if (blockIdx.x < NBLK) {
    int idx = blockIdx.x * 1024 + tid * 4;
    int4 v = *(const int4*)(hist + idx);
    int s0 = v.x, s1 = s0 + v.y, s2 = s1 + v.z, s3 = s2 + v.w;
    lds[tid] = s3;
    __syncthreads();
    int val = s3;
    for (int off = 1; off < 256; off <<= 1) {
      int n = (tid >= off) ? lds[tid - off] : 0;
      __syncthreads();
      val += n;
      lds[tid] = val;
      __syncthreads();
    }
    int excl = val - s3;
    int4 o;
    o.x = excl; o.y = excl + s0; o.z = excl + s1; o.w = excl + s2;
    *(int4*)(baseLocal + idx) = o;
    if (tid == 255) blockSum[blockIdx.x] = val;
  } else if (blockIdx.x == NBLK) {
#pragma unroll
    for (int it = 0; it < 24; it++) {
      int idx = it * 256 + tid;             // < 3*32*64 = 6144
      int ky = idx >> 11;
      int rem = idx & 2047;
      int n = rem >> 6;
      int kl = rem & 63;
      unsigned short v = 0;
      if (kl < 54) {
        int kx = kl / 18, ci = kl - kx * 18;
        v = f2bf(weight[((ky * 3 + kx) * CIN + ci) * OUT_CH + n]);
      }
      wprep[idx] = v;
    }
  }
  grid.sync();

  // ---- phase D: scan2 of 570 block totals on block 0 ----
  if (blockIdx.x == 0) {
    int idx = tid * 4;
    int a0 = (idx + 0 < NBLK) ? blockSum[idx + 0] : 0;
    int a1 = (idx + 1 < NBLK) ? blockSum[idx + 1] : 0;
    int a2 = (idx + 2 < NBLK) ? blockSum[idx + 2] : 0;
    int a3 = (idx + 3 < NBLK) ? blockSum[idx + 3] : 0;
    int s0 = a0, s1 = s0 + a1, s2 = s1 + a2, s3 = s2 + a3;
    lds[tid] = s3;
    __syncthreads();
    int val = s3;
    for (int off = 1; off < 256; off <<= 1) {
      int n = (tid >= off) ? lds[tid - off] : 0;
      __syncthreads();
      val += n;
      lds[tid] = val;
      __syncthreads();
    }
    int excl = val - s3;
    if (idx + 0 < NBLK) blockOffset[idx + 0] = excl;
    if (idx + 1 < NBLK) blockOffset[idx + 1] = excl + s0;
    if (idx + 2 < NBLK) blockOffset[idx + 2] = excl + s1;
    if (idx + 3 < NBLK) blockOffset[idx + 3] = excl + s2;
    if (tid == 255) blockOffset[NBLK] = val;  // = N_EV
  }
  grid.sync();

  // ---- phase E: payload scatter straight from registers ----
#pragma unroll
  for (int s = 0; s < 2; s++) {
    int k = key[s] & 0x7fffffff;
    int pos = baseLocal[k] + blockOffset[k >> 10] + rank[s];
    sortedFeat[(size_t)pos * 2] = w0[s];
    sortedFeat[(size_t)pos * 2 + 1] = w1[s];
    int i = gtid + s * COOP_TOTAL;
    sortedMeta[pos] = i | (key[s] & (int)0x80000000);
  }
}

// ---- C: fused per-tile accum (bf16 LDS halo) + MFMA conv + event scatter ---
// (round-0 version, verbatim: sequential prepacked sortedFeat reads)
__global__ __launch_bounds__(256) void fused_conv_kernel(
    const uint4* __restrict__ sortedFeat, const int* __restrict__ sortedMeta,
    const int* __restrict__ baseLocal, const int* __restrict__ blockOffset,
    const unsigned short* __restrict__ wprep, const float* __restrict__ bias,
    float* __restrict__ out) {
  __shared__ unsigned smem[128 * OPITCH];  // 16896 B (>= 3072 dwords for halo)
  __shared__ int ibase[TH * TW];
  __shared__ int icnt[TH * TW];

  int blk = blockIdx.x;
  int xt = blk % NXT_TILES;
  int rem = blk / NXT_TILES;
  int yt = rem % NYT_TILES;
  int b = rem / NYT_TILES;
  int x0 = xt * TW, y0 = yt * TH;
  int tid = threadIdx.x;

  if (tid < 12) smem[3060 + tid] = 0;  // zero A-read overrun pad

  // ---- stage 1: build normalized bf16 dense halo in LDS ----
  for (int h = tid; h < HH_ * HW_; h += 256) {
    int hy = h / HW_, hx = h % HW_;
    int gy = y0 - 1 + hy, gx = x0 - 1 + hx;
    float acc[CIN];
#pragma unroll
    for (int k = 0; k < CIN; k++) acc[k] = 0.0f;
    int c = 0, base = 0;
    if (gy >= 0 && gy < Hh && gx >= 0 && gx < Ww) {
      int p = (b * Hh + gy) * Ww + gx;
      int bo = blockOffset[p >> 10];
      base = baseLocal[p] + bo;
      int nxt = ((p & 1023) != 1023) ? (baseLocal[p + 1] + bo)
                                     : blockOffset[(p >> 10) + 1];
      c = nxt - base;
      for (int j = 0; j < c; j++) {
        int e = sortedMeta[base + j];
        float pol = (float)((unsigned)e >> 31);
        acc[0] += pol;
        acc[1] += 1.0f - pol;
        uint4 w0 = sortedFeat[(size_t)(base + j) * 2];
        uint4 w1 = sortedFeat[(size_t)(base + j) * 2 + 1];
        acc[2] += bf2f((unsigned short)w0.x);  acc[3] += bf2f((unsigned short)(w0.x >> 16));
        acc[4] += bf2f((unsigned short)w0.y);  acc[5] += bf2f((unsigned short)(w0.y >> 16));
        acc[6] += bf2f((unsigned short)w0.z);  acc[7] += bf2f((unsigned short)(w0.z >> 16));
        acc[8] += bf2f((unsigned short)w0.w);  acc[9] += bf2f((unsigned short)(w0.w >> 16));
        acc[10] += bf2f((unsigned short)w1.x); acc[11] += bf2f((unsigned short)(w1.x >> 16));
        acc[12] += bf2f((unsigned short)w1.y); acc[13] += bf2f((unsigned short)(w1.y >> 16));
        acc[14] += bf2f((unsigned short)w1.z); acc[15] += bf2f((unsigned short)(w1.z >> 16));
        acc[16] += bf2f((unsigned short)w1.w); acc[17] += bf2f((unsigned short)(w1.w >> 16));
      }
    }
    float inv = 1.0f / fmaxf((float)c, 1.0f);
    unsigned* row = smem + 9 * h;  // 18 bf16 = 9 dwords
#pragma unroll
    for (int k = 0; k < 9; k++)
      row[k] = (unsigned)f2bf(acc[2 * k] * inv) |
               ((unsigned)f2bf(acc[2 * k + 1] * inv) << 16);
    if (hx >= 1 && hx <= TW && hy >= 1 && hy <= TH) {
      int t = (hy - 1) * TW + (hx - 1);
      ibase[t] = base;
      icnt[t] = c;
    }
  }
  __syncthreads();

  // ---- stage 2: MFMA GEMM from LDS halo (ky-outer to cut VGPR) ----
  int wv = tid >> 6, lane = tid & 63;
  int quad = lane >> 4, lrow = lane & 15;

  f32x4 accf[4][2];
#pragma unroll
  for (int i = 0; i < 4; i++)
#pragma unroll
    for (int nt = 0; nt < 2; nt++) accf[i][nt] = (f32x4){0.f, 0.f, 0.f, 0.f};

  const unsigned* hp = smem;
#pragma unroll
  for (int ky = 0; ky < 3; ky++) {
    // B fragments for this ky: one 16B load each (prepacked [ky][n][64])
    bf16x8 bfr[2][2];  // [khalf][ntile]
#pragma unroll
    for (int kh = 0; kh < 2; kh++)
#pragma unroll
      for (int nt = 0; nt < 2; nt++) {
        int n = nt * 16 + lrow;
        bfr[kh][nt] = *(const bf16x8*)(wprep + ((ky * 32 + n) << 6) +
                                       kh * 32 + quad * 8);
      }
#pragma unroll
    for (int i = 0; i < 4; i++) {  // m-tiles of this wave
      int t0 = (wv * 4 + i) * 16;
      int ox = (t0 & 31) + lrow;   // A: m = lane&15
      int oy = t0 >> 5;
      int idx0 = ((oy + ky) * HW_ + ox) * CIN;  // even (shorts)
#pragma unroll
      for (int kh = 0; kh < 2; kh++) {
        union { bf16x8 v; unsigned u[4]; } a;
        int ui = (idx0 >> 1) + kh * 16 + quad * 4;
        a.u[0] = hp[ui]; a.u[1] = hp[ui + 1];
        a.u[2] = hp[ui + 2]; a.u[3] = hp[ui + 3];
        accf[i][0] = __builtin_amdgcn_mfma_f32_16x16x32_bf16(
            a.v, bfr[kh][0], accf[i][0], 0, 0, 0);
        accf[i][1] = __builtin_amdgcn_mfma_f32_16x16x32_bf16(
            a.v, bfr[kh][1], accf[i][1], 0, 0, 0);
      }
    }
  }
  __syncthreads();  // halo dead; smem becomes out repack (128 rows x 33)

  // ---- stages 3+4, chunked (2 x 32 pixels per wave) to halve LDS ----
  float* outsh = (float*)smem;
  float bn0 = bias[lrow], bn1 = bias[16 + lrow];  // D: col = lane&15
  int gx = x0 + (tid & 31);
  int c = icnt[tid];
  int base = ibase[tid];
#pragma unroll
  for (int ch = 0; ch < 2; ch++) {
#pragma unroll
    for (int ii = 0; ii < 2; ii++) {
      int i = ch * 2 + ii;
      int lidx = ii * 16 + quad * 4;         // local row within chunk [0,32)
      int row = wv * 32 + lidx;
#pragma unroll
      for (int r = 0; r < 4; r++) {
        outsh[(row + r) * OPITCH + lrow] = accf[i][0][r] + bn0;
        outsh[(row + r) * OPITCH + 16 + lrow] = accf[i][1][r] + bn1;
      }
    }
    __syncthreads();
    if (((tid >> 5) & 1) == ch && gx < Ww && c > 0) {
      int row = (tid >> 6) * 32 + ((tid & 63) - ch * 32);
      const float* rp = outsh + row * OPITCH;
      float4 o0 = make_float4(rp[0], rp[1], rp[2], rp[3]);
      float4 o1 = make_float4(rp[4], rp[5], rp[6], rp[7]);
      float4 o2 = make_float4(rp[8], rp[9], rp[10], rp[11]);
      float4 o3 = make_float4(rp[12], rp[13], rp[14], rp[15]);
      float4 o4 = make_float4(rp[16], rp[17], rp[18], rp[19]);
      float4 o5 = make_float4(rp[20], rp[21], rp[22], rp[23]);
      float4 o6 = make_float4(rp[24], rp[25], rp[26], rp[27]);
      float4 o7 = make_float4(rp[28], rp[29], rp[30], rp[31]);
      for (int j = 0; j < c; j++) {
        int ev = sortedMeta[base + j] & 0x7fffffff;
        float4* op = (float4*)(out + (size_t)ev * OUT_CH);
        op[0] = o0; op[1] = o1; op[2] = o2; op[3] = o3;
        op[4] = o4; op[5] = o5; op[6] = o6; op[7] = o7;
      }
    }
    __syncthreads();
  }
}

extern "C" void kernel_launch(void* const* d_in, const int* in_sizes, int n_in,
                              void* d_out, int out_size, void* d_ws,
                              size_t ws_size, hipStream_t stream) {
  const float* events = (const float*)d_in[0];
  const float* features = (const float*)d_in[1];
  const float* weight = (const float*)d_in[2];
  const float* bias = (const float*)d_in[3];
  const int* offsets = (const int*)d_in[4];
  float* out = (float*)d_out;

  uint4* sortedFeat = (uint4*)d_ws;                        // N_EV*2 uint4
  int* sortedMeta = (int*)(sortedFeat + (size_t)N_EV * 2); // N_EV
  int* hist = sortedMeta + N_EV;                           // NSEG
  int* baseLocal = hist + NSEG;                            // NSEG
  int* blockOffset = baseLocal + NSEG;                     // NBLK+1 (pad 1024)
  int* blockSum = blockOffset + 1024;                      // NBLK (pad 1024)
  unsigned short* wprep = (unsigned short*)(blockSum + 1024);  // 6144 ushort

  void* args[] = {(void*)&events,   (void*)&features, (void*)&weight,
                  (void*)&offsets,  (void*)&hist,     (void*)&baseLocal,
                  (void*)&blockOffset, (void*)&blockSum, (void*)&wprep,
                  (void*)&sortedFeat, (void*)&sortedMeta};
  hipLaunchCooperativeKernel((const void*)prep_kernel, dim3(COOP_BLOCKS),
                             dim3(COOP_THREADS), args, 0, stream);
  fused_conv_kernel<<<Bb * NYT_TILES * NXT_TILES, 256, 0, stream>>>(
      sortedFeat, sortedMeta, baseLocal, blockOffset, wprep, bias, out);
}

// Round 4
// 191.989 us; speedup vs baseline: 2.8439x; 2.8439x over previous
//
#include <hip/hip_runtime.h>

#define Hh 240
#define Ww 304
#define IN_CH 16
#define OUT_CH 32
#define Bb 8
#define N_PER 65536
#define N_EV (Bb * N_PER)      // 524288
#define CIN (IN_CH + 2)        // 18
#define NSEG (Bb * Hh * Ww)    // 583680 = 570 * 1024
#define NBLK 570               // scan blocks of 1024 elems

// fused conv tiling
#define TW 32
#define TH 8
#define HW_ 34                 // TW + 2 halo
#define HH_ 10                 // TH + 2 halo
#define NXT_TILES 10           // ceil(304/32)
#define NYT_TILES 30           // 240/8
#define OPITCH 33              // out repack pitch (f32)

typedef __attribute__((ext_vector_type(8))) short bf16x8;
typedef __attribute__((ext_vector_type(4))) float f32x4;

__device__ __forceinline__ unsigned short f2bf(float x) {
  unsigned u = __float_as_uint(x);
  unsigned r = u + 0x7fffu + ((u >> 16) & 1u);  // RNE
  return (unsigned short)(r >> 16);
}
__device__ __forceinline__ float bf2f(unsigned short b) {
  return __uint_as_float(((unsigned)b) << 16);
}

// ---- A: histogram + rank per event (one atomic pass) -----------------------
__global__ __launch_bounds__(256) void hist_rank_kernel(
    const float* __restrict__ events, const int* __restrict__ offsets,
    int* __restrict__ hist, int* __restrict__ keyArr, int* __restrict__ rankArr) {
  int i = blockIdx.x * blockDim.x + threadIdx.x;
  float4 ev = ((const float4*)events)[i];
  int yi = (int)rintf(ev.y * (float)Hh);
  yi = min(max(yi, 0), Hh - 1);
  int xi = (int)rintf(ev.x * (float)Ww);
  xi = min(max(xi, 0), Ww - 1);
  int b = 0;
#pragma unroll
  for (int j = 0; j < Bb; j++) b += (offsets[j] <= i) ? 1 : 0;
  int key = (b * Hh + yi) * Ww + xi;
  int pol = (ev.w != 0.0f) ? 1 : 0;
  keyArr[i] = key | (pol << 31);
  rankArr[i] = atomicAdd(&hist[key], 1);
}

// ---- S: single-dispatch scan. Blocks 0..569: local exclusive scan of 1024
// hist entries; block offset claimed from a global atomic cursor (arrival
// order — consumers only need disjoint contiguous ranges + blockEnd).
// Block 570: pack weights to [ky][n][64] bf16, zero-padded k>=54.
__global__ __launch_bounds__(256) void scan_fused_kernel(
    const int* __restrict__ hist, int* __restrict__ baseLocal,
    int* __restrict__ blockOffset, int* __restrict__ blockEnd,
    int* __restrict__ cursor, const float* __restrict__ weight,
    unsigned short* __restrict__ wprep) {
  int b = blockIdx.x, t = threadIdx.x;
  if (b == NBLK) {
#pragma unroll
    for (int it = 0; it < 24; it++) {
      int idx = it * 256 + t;               // < 3*32*64 = 6144
      int ky = idx >> 11;
      int rem = idx & 2047;
      int n = rem >> 6;
      int kl = rem & 63;
      unsigned short v = 0;
      if (kl < 54) {
        int kx = kl / 18, ci = kl - kx * 18;
        v = f2bf(weight[((ky * 3 + kx) * CIN + ci) * OUT_CH + n]);
      }
      wprep[idx] = v;
    }
    return;
  }
  __shared__ int lds[256];
  int idx = b * 1024 + t * 4;
  int4 v = *(const int4*)(hist + idx);
  int s0 = v.x, s1 = s0 + v.y, s2 = s1 + v.z, s3 = s2 + v.w;
  lds[t] = s3;
  __syncthreads();
  int val = s3;
  for (int off = 1; off < 256; off <<= 1) {
    int n = (t >= off) ? lds[t - off] : 0;
    __syncthreads();
    val += n;
    lds[t] = val;
    __syncthreads();
  }
  int excl = val - s3;
  int4 o;
  o.x = excl; o.y = excl + s0; o.z = excl + s1; o.w = excl + s2;
  *(int4*)(baseLocal + idx) = o;
  if (t == 255) {  // val == block total here
    int start = atomicAdd(cursor, val);
    blockOffset[b] = start;
    blockEnd[b] = start + val;
  }
}

// ---- B: scatter features (bf16) + meta into sorted order -------------------
__global__ __launch_bounds__(256) void scatter_feat_kernel(
    const float* __restrict__ features, const int* __restrict__ keyArr,
    const int* __restrict__ rankArr, const int* __restrict__ baseLocal,
    const int* __restrict__ blockOffset, uint4* __restrict__ sortedFeat,
    int* __restrict__ sortedMeta) {
  int i = blockIdx.x * blockDim.x + threadIdx.x;
  int meta = keyArr[i];
  int key = meta & 0x7fffffff;
  int pos = baseLocal[key] + blockOffset[key >> 10] + rankArr[i];
  const float4* f = (const float4*)(features + (size_t)i * IN_CH);
  float4 f0 = f[0], f1 = f[1], f2 = f[2], f3 = f[3];
  uint4 w0, w1;
  w0.x = (unsigned)f2bf(f0.x) | ((unsigned)f2bf(f0.y) << 16);
  w0.y = (unsigned)f2bf(f0.z) | ((unsigned)f2bf(f0.w) << 16);
  w0.z = (unsigned)f2bf(f1.x) | ((unsigned)f2bf(f1.y) << 16);
  w0.w = (unsigned)f2bf(f1.z) | ((unsigned)f2bf(f1.w) << 16);
  w1.x = (unsigned)f2bf(f2.x) | ((unsigned)f2bf(f2.y) << 16);
  w1.y = (unsigned)f2bf(f2.z) | ((unsigned)f2bf(f2.w) << 16);
  w1.z = (unsigned)f2bf(f3.x) | ((unsigned)f2bf(f3.y) << 16);
  w1.w = (unsigned)f2bf(f3.z) | ((unsigned)f2bf(f3.w) << 16);
  sortedFeat[(size_t)pos * 2] = w0;
  sortedFeat[(size_t)pos * 2 + 1] = w1;
  sortedMeta[pos] = i | (meta & 0x80000000);
}

// ---- C: fused per-tile accum (bf16 LDS halo) + MFMA conv + event scatter ---
// (round-0 version; only change: end-of-block nxt reads blockEnd)
__global__ __launch_bounds__(256) void fused_conv_kernel(
    const uint4* __restrict__ sortedFeat, const int* __restrict__ sortedMeta,
    const int* __restrict__ baseLocal, const int* __restrict__ blockOffset,
    const int* __restrict__ blockEnd, const unsigned short* __restrict__ wprep,
    const float* __restrict__ bias, float* __restrict__ out) {
  __shared__ unsigned smem[128 * OPITCH];  // 16896 B (>= 3072 dwords for halo)
  __shared__ int ibase[TH * TW];
  __shared__ int icnt[TH * TW];

  int blk = blockIdx.x;
  int xt = blk % NXT_TILES;
  int rem = blk / NXT_TILES;
  int yt = rem % NYT_TILES;
  int b = rem / NYT_TILES;
  int x0 = xt * TW, y0 = yt * TH;
  int tid = threadIdx.x;

  if (tid < 12) smem[3060 + tid] = 0;  // zero A-read overrun pad

  // ---- stage 1: build normalized bf16 dense halo in LDS ----
  for (int h = tid; h < HH_ * HW_; h += 256) {
    int hy = h / HW_, hx = h % HW_;
    int gy = y0 - 1 + hy, gx = x0 - 1 + hx;
    float acc[CIN];
#pragma unroll
    for (int k = 0; k < CIN; k++) acc[k] = 0.0f;
    int c = 0, base = 0;
    if (gy >= 0 && gy < Hh && gx >= 0 && gx < Ww) {
      int p = (b * Hh + gy) * Ww + gx;
      int bo = blockOffset[p >> 10];
      base = baseLocal[p] + bo;
      int nxt = ((p & 1023) != 1023) ? (baseLocal[p + 1] + bo)
                                     : blockEnd[p >> 10];
      c = nxt - base;
      for (int j = 0; j < c; j++) {
        int e = sortedMeta[base + j];
        float pol = (float)((unsigned)e >> 31);
        acc[0] += pol;
        acc[1] += 1.0f - pol;
        uint4 w0 = sortedFeat[(size_t)(base + j) * 2];
        uint4 w1 = sortedFeat[(size_t)(base + j) * 2 + 1];
        acc[2] += bf2f((unsigned short)w0.x);  acc[3] += bf2f((unsigned short)(w0.x >> 16));
        acc[4] += bf2f((unsigned short)w0.y);  acc[5] += bf2f((unsigned short)(w0.y >> 16));
        acc[6] += bf2f((unsigned short)w0.z);  acc[7] += bf2f((unsigned short)(w0.z >> 16));
        acc[8] += bf2f((unsigned short)w0.w);  acc[9] += bf2f((unsigned short)(w0.w >> 16));
        acc[10] += bf2f((unsigned short)w1.x); acc[11] += bf2f((unsigned short)(w1.x >> 16));
        acc[12] += bf2f((unsigned short)w1.y); acc[13] += bf2f((unsigned short)(w1.y >> 16));
        acc[14] += bf2f((unsigned short)w1.z); acc[15] += bf2f((unsigned short)(w1.z >> 16));
        acc[16] += bf2f((unsigned short)w1.w); acc[17] += bf2f((unsigned short)(w1.w >> 16));
      }
    }
    float inv = 1.0f / fmaxf((float)c, 1.0f);
    unsigned* row = smem + 9 * h;  // 18 bf16 = 9 dwords
#pragma unroll
    for (int k = 0; k < 9; k++)
      row[k] = (unsigned)f2bf(acc[2 * k] * inv) |
               ((unsigned)f2bf(acc[2 * k + 1] * inv) << 16);
    if (hx >= 1 && hx <= TW && hy >= 1 && hy <= TH) {
      int t = (hy - 1) * TW + (hx - 1);
      ibase[t] = base;
      icnt[t] = c;
    }
  }
  __syncthreads();

  // ---- stage 2: MFMA GEMM from LDS halo (ky-outer to cut VGPR) ----
  int wv = tid >> 6, lane = tid & 63;
  int quad = lane >> 4, lrow = lane & 15;

  f32x4 accf[4][2];
#pragma unroll
  for (int i = 0; i < 4; i++)
#pragma unroll
    for (int nt = 0; nt < 2; nt++) accf[i][nt] = (f32x4){0.f, 0.f, 0.f, 0.f};

  const unsigned* hp = smem;
#pragma unroll
  for (int ky = 0; ky < 3; ky++) {
    // B fragments for this ky: one 16B load each (prepacked [ky][n][64])
    bf16x8 bfr[2][2];  // [khalf][ntile]
#pragma unroll
    for (int kh = 0; kh < 2; kh++)
#pragma unroll
      for (int nt = 0; nt < 2; nt++) {
        int n = nt * 16 + lrow;
        bfr[kh][nt] = *(const bf16x8*)(wprep + ((ky * 32 + n) << 6) +
                                       kh * 32 + quad * 8);
      }
#pragma unroll
    for (int i = 0; i < 4; i++) {  // m-tiles of this wave
      int t0 = (wv * 4 + i) * 16;
      int ox = (t0 & 31) + lrow;   // A: m = lane&15
      int oy = t0 >> 5;
      int idx0 = ((oy + ky) * HW_ + ox) * CIN;  // even (shorts)
#pragma unroll
      for (int kh = 0; kh < 2; kh++) {
        union { bf16x8 v; unsigned u[4]; } a;
        int ui = (idx0 >> 1) + kh * 16 + quad * 4;
        a.u[0] = hp[ui]; a.u[1] = hp[ui + 1];
        a.u[2] = hp[ui + 2]; a.u[3] = hp[ui + 3];
        accf[i][0] = __builtin_amdgcn_mfma_f32_16x16x32_bf16(
            a.v, bfr[kh][0], accf[i][0], 0, 0, 0);
        accf[i][1] = __builtin_amdgcn_mfma_f32_16x16x32_bf16(
            a.v, bfr[kh][1], accf[i][1], 0, 0, 0);
      }
    }
  }
  __syncthreads();  // halo dead; smem becomes out repack (128 rows x 33)

  // ---- stages 3+4, chunked (2 x 32 pixels per wave) to halve LDS ----
  float* outsh = (float*)smem;
  float bn0 = bias[lrow], bn1 = bias[16 + lrow];  // D: col = lane&15
  int gx = x0 + (tid & 31);
  int c = icnt[tid];
  int base = ibase[tid];
#pragma unroll
  for (int ch = 0; ch < 2; ch++) {
#pragma unroll
    for (int ii = 0; ii < 2; ii++) {
      int i = ch * 2 + ii;
      int lidx = ii * 16 + quad * 4;         // local row within chunk [0,32)
      int row = wv * 32 + lidx;
#pragma unroll
      for (int r = 0; r < 4; r++) {
        outsh[(row + r) * OPITCH + lrow] = accf[i][0][r] + bn0;
        outsh[(row + r) * OPITCH + 16 + lrow] = accf[i][1][r] + bn1;
      }
    }
    __syncthreads();
    if (((tid >> 5) & 1) == ch && gx < Ww && c > 0) {
      int row = (tid >> 6) * 32 + ((tid & 63) - ch * 32);
      const float* rp = outsh + row * OPITCH;
      float4 o0 = make_float4(rp[0], rp[1], rp[2], rp[3]);
      float4 o1 = make_float4(rp[4], rp[5], rp[6], rp[7]);
      float4 o2 = make_float4(rp[8], rp[9], rp[10], rp[11]);
      float4 o3 = make_float4(rp[12], rp[13], rp[14], rp[15]);
      float4 o4 = make_float4(rp[16], rp[17], rp[18], rp[19]);
      float4 o5 = make_float4(rp[20], rp[21], rp[22], rp[23]);
      float4 o6 = make_float4(rp[24], rp[25], rp[26], rp[27]);
      float4 o7 = make_float4(rp[28], rp[29], rp[30], rp[31]);
      for (int j = 0; j < c; j++) {
        int ev = sortedMeta[base + j] & 0x7fffffff;
        float4* op = (float4*)(out + (size_t)ev * OUT_CH);
        op[0] = o0; op[1] = o1; op[2] = o2; op[3] = o3;
        op[4] = o4; op[5] = o5; op[6] = o6; op[7] = o7;
      }
    }
    __syncthreads();
  }
}

extern "C" void kernel_launch(void* const* d_in, const int* in_sizes, int n_in,
                              void* d_out, int out_size, void* d_ws,
                              size_t ws_size, hipStream_t stream) {
  const float* events = (const float*)d_in[0];
  const float* features = (const float*)d_in[1];
  const float* weight = (const float*)d_in[2];
  const float* bias = (const float*)d_in[3];
  const int* offsets = (const int*)d_in[4];
  float* out = (float*)d_out;

  uint4* sortedFeat = (uint4*)d_ws;                   // N_EV * 32B
  int* sortedMeta = (int*)(sortedFeat + (size_t)N_EV * 2);  // N_EV
  int* keyArr = sortedMeta + N_EV;                    // N_EV
  int* rankArr = keyArr + N_EV;                       // N_EV
  int* hist = rankArr + N_EV;                         // NSEG
  int* cursor = hist + NSEG;                          // 4 (memset with hist)
  int* baseLocal = cursor + 4;                        // NSEG
  int* blockOffset = baseLocal + NSEG;                // NBLK (pad 1024)
  int* blockEnd = blockOffset + 1024;                 // NBLK (pad 1024)
  unsigned short* wprep = (unsigned short*)(blockEnd + 1024);  // 6144 ushort

  hipMemsetAsync(hist, 0, (size_t)(NSEG + 4) * sizeof(int), stream);

  hist_rank_kernel<<<N_EV / 256, 256, 0, stream>>>(events, offsets, hist,
                                                   keyArr, rankArr);
  scan_fused_kernel<<<NBLK + 1, 256, 0, stream>>>(
      hist, baseLocal, blockOffset, blockEnd, cursor, weight, wprep);
  scatter_feat_kernel<<<N_EV / 256, 256, 0, stream>>>(
      features, keyArr, rankArr, baseLocal, blockOffset, sortedFeat, sortedMeta);
  fused_conv_kernel<<<Bb * NYT_TILES * NXT_TILES, 256, 0, stream>>>(
      sortedFeat, sortedMeta, baseLocal, blockOffset, blockEnd, wprep, bias,
      out);
}